// Round 3
// baseline (163.275 us; speedup 1.0000x reference)
//
#include <hip/hip_runtime.h>
#include <hip/hip_bf16.h>

// SynthesisLayer: B=8, CIN=256, COUT=256, H=W=64, WDIM=512, K=3
// y = lrelu( demod * conv3x3(x*s, cw/48) + nw*noise + bias )
//
// Round-3 bisect build: conv staging is plain reg-staged ds_write (NO
// global_load_lds, NO swizzle, NO zbuf) to localize the round-2 absmax=4.06.

typedef __attribute__((ext_vector_type(8))) short bf16x8;
typedef __attribute__((ext_vector_type(4))) float f32x4;

#define INV_SQRT_WDIM 0.04419417382415922f  // 1/sqrt(512)

// K1: s[b][c] = dot(w[b,:], sw[c,:]) / sqrt(512) + sb[c]
__global__ __launch_bounds__(256)
void style_kernel(const float* __restrict__ w, const float* __restrict__ sw,
                  const float* __restrict__ sb, float* __restrict__ s) {
  const int b = blockIdx.x;
  const int c = threadIdx.x;
  float acc = 0.f;
#pragma unroll 8
  for (int d = 0; d < 512; ++d) acc += w[b * 512 + d] * sw[c * 512 + d];
  s[b * 256 + c] = acc * INV_SQRT_WDIM + sb[c];
}

// K2: demod[b][o] = rsqrt( (1/2304) * sum_i (sum_t cw[o,i,t]^2) * s[b,i]^2 + 1e-8 )
__global__ __launch_bounds__(256)
void demod_kernel(const float* __restrict__ cw, const float* __restrict__ s,
                  float* __restrict__ demod) {
  const int o = blockIdx.x;
  const int i = threadIdx.x;
  float w2 = 0.f;
#pragma unroll
  for (int t = 0; t < 9; ++t) {
    float v = cw[(o * 256 + i) * 9 + t];
    w2 += v * v;
  }
  __shared__ float red[4];
  for (int b = 0; b < 8; ++b) {
    float sv = s[b * 256 + i];
    float val = w2 * sv * sv;
#pragma unroll
    for (int off = 32; off > 0; off >>= 1) val += __shfl_down(val, off);
    if ((i & 63) == 0) red[i >> 6] = val;
    __syncthreads();
    if (i == 0) {
      float tot = red[0] + red[1] + red[2] + red[3];
      demod[b * 256 + o] = rsqrtf(tot * (1.0f / 2304.0f) + 1e-8f);
    }
    __syncthreads();
  }
}

// K3: wt[t][o][i] = bf16( cw[o][i][t] / 48 )   (i-contiguous for MFMA A-frags)
__global__ __launch_bounds__(256)
void wtrans_kernel(const float* __restrict__ cw, __hip_bfloat16* __restrict__ wt) {
  const int e = blockIdx.x * 256 + threadIdx.x;  // 9*256*256 = 589824
  const int tap = e >> 16;
  const int o = (e >> 8) & 255;
  const int i = e & 255;
  wt[e] = __float2bfloat16(cw[(o * 256 + i) * 9 + tap] * (1.0f / 48.0f));
}

// K4: xt[b][h][w][i] = bf16( x[b][i][h][w] * s[b][i] )   (NHWC, i-contiguous)
__global__ __launch_bounds__(256)
void xmod_kernel(const float* __restrict__ x, const float* __restrict__ s,
                 __hip_bfloat16* __restrict__ xt) {
  const int h = blockIdx.x;
  const int b = blockIdx.y;
  __shared__ __hip_bfloat16 tile[256 * 66];
  const int t = threadIdx.x;
  const int wl4 = (t & 15) * 4;
#pragma unroll 4
  for (int p = 0; p < 16; ++p) {
    const int i = p * 16 + (t >> 4);
    const float4 v = *(const float4*)&x[((b * 256 + i) * 64 + h) * 64 + wl4];
    const float sv = s[b * 256 + i];
    const int wsw = wl4 ^ (((i >> 3) & 7) << 3);
    unsigned lo = ((unsigned)__bfloat16_as_ushort(__float2bfloat16(v.y * sv)) << 16) |
                  (unsigned)__bfloat16_as_ushort(__float2bfloat16(v.x * sv));
    unsigned hi = ((unsigned)__bfloat16_as_ushort(__float2bfloat16(v.w * sv)) << 16) |
                  (unsigned)__bfloat16_as_ushort(__float2bfloat16(v.z * sv));
    *(unsigned*)&tile[i * 66 + wsw] = lo;
    *(unsigned*)&tile[i * 66 + wsw + 2] = hi;
  }
  __syncthreads();
#pragma unroll 2
  for (int p = 0; p < 8; ++p) {
    const int w = p * 8 + (t >> 5);
    const int c = t & 31;
    ushort out8[8];
#pragma unroll
    for (int j = 0; j < 8; ++j) {
      const int i = c * 8 + j;
      const int wsw = w ^ (((i >> 3) & 7) << 3);
      out8[j] = __bfloat16_as_ushort(tile[i * 66 + wsw]);
    }
    *(uint4*)&xt[((b * 64 + h) * 64 + w) * 256 + c * 8] = *(uint4*)out8;
  }
}

// K5 (bisect build): conv as 9 shifted GEMMs, mfma_f32_16x16x32_bf16.
// Block: 64 oc x (4 rows x 64 w), b fixed. 4 waves.
// LDS linear, reg-staged: xlds[6][64][32], wlds[9][64][32].
__global__ __launch_bounds__(256, 2)
void conv_mfma_kernel(const __hip_bfloat16* __restrict__ xt,
                      const __hip_bfloat16* __restrict__ wt,
                      const float* __restrict__ demod,
                      const float* __restrict__ noise,
                      const float* __restrict__ nw,
                      const float* __restrict__ bias,
                      float* __restrict__ out) {
  __shared__ __hip_bfloat16 xlds[6 * 64 * 32] __attribute__((aligned(16)));
  __shared__ __hip_bfloat16 wlds[9 * 64 * 32] __attribute__((aligned(16)));

  const int tid = threadIdx.x;
  const int lane = tid & 63;
  const int wv = tid >> 6;

  const int h0 = blockIdx.x * 4;   // 16 spatial tiles
  const int oc0 = blockIdx.y * 64; // 4 oc tiles
  const int b = blockIdx.z;        // 8 batches

  // Linear fragment offsets (no swizzle): k-group = lane>>4
  const int abase = (lane & 15) * 32 + 8 * (lane >> 4);

  int boff[4][3];
  bool bok[4][3];
#pragma unroll
  for (int q = 0; q < 4; ++q)
#pragma unroll
    for (int tj = 0; tj < 3; ++tj) {
      int wx = q * 16 + (lane & 15) + tj - 1;
      bool ok = (unsigned)wx < 64u;
      int wc = ok ? wx : 0;
      boff[q][tj] = wc * 32 + 8 * (lane >> 4);
      bok[q][tj] = ok;
    }

  const f32x4 zero4 = {0.f, 0.f, 0.f, 0.f};
  const bf16x8 zerov = {0, 0, 0, 0, 0, 0, 0, 0};
  f32x4 acc[4][4];
#pragma unroll
  for (int m = 0; m < 4; ++m)
#pragma unroll
    for (int q = 0; q < 4; ++q) acc[m][q] = zero4;

  for (int cc = 0; cc < 8; ++cc) {
    const int c0 = cc * 32;
    __syncthreads();  // previous chunk's LDS readers done

    // stage X: 1536 16B-groups, 6 per thread. group gX = r*256 + w*4 + g
#pragma unroll
    for (int k = 0; k < 6; ++k) {
      const int gX = tid + k * 256;
      const int r = gX >> 8;
      const int w = (gX >> 2) & 63;
      const int g = gX & 3;
      const int gr = h0 - 1 + r;
      uint4 v = make_uint4(0u, 0u, 0u, 0u);
      if ((unsigned)gr < 64u)
        v = *(const uint4*)&xt[((b * 64 + gr) * 64 + w) * 256 + c0 + 8 * g];
      *(uint4*)&xlds[gX * 8] = v;
    }
    // stage W: 2304 16B-groups, 9 per thread. group gW = t9*256 + o*4 + g
#pragma unroll
    for (int k = 0; k < 9; ++k) {
      const int gW = tid + k * 256;
      const int t9 = gW >> 8;
      const int o = (gW >> 2) & 63;
      const int g = gW & 3;
      uint4 v = *(const uint4*)&wt[t9 * 65536 + (oc0 + o) * 256 + c0 + 8 * g];
      *(uint4*)&wlds[gW * 8] = v;
    }
    __syncthreads();  // staged data visible

#pragma unroll
    for (int ti = 0; ti < 3; ++ti) {
#pragma unroll
      for (int tj = 0; tj < 3; ++tj) {
        const int t = ti * 3 + tj;
        bf16x8 av[4];
#pragma unroll
        for (int m = 0; m < 4; ++m)
          av[m] = *(const bf16x8*)&wlds[t * 2048 + m * 512 + abase];
#pragma unroll
        for (int q = 0; q < 4; ++q) {
          bf16x8 bv = *(const bf16x8*)&xlds[(wv + ti) * 2048 + boff[q][tj]];
          if (!bok[q][tj]) bv = zerov;
#pragma unroll
          for (int m = 0; m < 4; ++m)
            acc[m][q] = __builtin_amdgcn_mfma_f32_16x16x32_bf16(av[m], bv, acc[m][q], 0, 0, 0);
        }
      }
    }
  }

  // epilogue: C/D layout col=lane&15 (w), row=4*(lane>>4)+reg (oc offset)
  const int hrow = h0 + wv;
  float nzv[4];
#pragma unroll
  for (int q = 0; q < 4; ++q)
    nzv[q] = noise[b * 4096 + hrow * 64 + q * 16 + (lane & 15)];
#pragma unroll
  for (int m = 0; m < 4; ++m) {
#pragma unroll
    for (int reg = 0; reg < 4; ++reg) {
      const int oc = oc0 + m * 16 + (lane >> 4) * 4 + reg;
      const float dm = demod[b * 256 + oc];
      const float nwv = nw[oc];
      const float bvv = bias[oc];
#pragma unroll
      for (int q = 0; q < 4; ++q) {
        float v = acc[m][q][reg] * dm + nwv * nzv[q] + bvv;
        v = (v >= 0.f) ? v : 0.2f * v;
        out[((b * 256 + oc) * 64 + hrow) * 64 + q * 16 + (lane & 15)] = v;
      }
    }
  }
}

extern "C" void kernel_launch(void* const* d_in, const int* in_sizes, int n_in,
                              void* d_out, int out_size, void* d_ws, size_t ws_size,
                              hipStream_t stream) {
  const float* x     = (const float*)d_in[0];  // [8,256,64,64]
  const float* w     = (const float*)d_in[1];  // [8,512]
  const float* noise = (const float*)d_in[2];  // [8,1,64,64]
  const float* sw    = (const float*)d_in[3];  // [256,512]
  const float* sb    = (const float*)d_in[4];  // [256]
  const float* cw    = (const float*)d_in[5];  // [256,256,3,3]
  const float* nw    = (const float*)d_in[6];  // [256]
  const float* bias  = (const float*)d_in[7];  // [256]
  float* out = (float*)d_out;                  // [8,256,64,64]

  char* ws = (char*)d_ws;
  float* s            = (float*)(ws);            // 8 KB
  float* demod        = (float*)(ws + 8192);     // 8 KB
  __hip_bfloat16* wt  = (__hip_bfloat16*)(ws + 16384);    // 1.18 MB
  __hip_bfloat16* xt  = (__hip_bfloat16*)(ws + 1196032);  // 16.8 MB

  style_kernel<<<8, 256, 0, stream>>>(w, sw, sb, s);
  demod_kernel<<<256, 256, 0, stream>>>(cw, s, demod);
  wtrans_kernel<<<2304, 256, 0, stream>>>(cw, wt);
  xmod_kernel<<<dim3(64, 8), 256, 0, stream>>>(x, s, xt);
  conv_mfma_kernel<<<dim3(16, 4, 8), 256, 0, stream>>>(
      xt, wt, demod, noise, nw, bias, out);
}

// Round 4
// 153.993 us; speedup vs baseline: 1.0603x; 1.0603x over previous
//
#include <hip/hip_runtime.h>
#include <hip/hip_bf16.h>

// SynthesisLayer: B=8, CIN=256, COUT=256, H=W=64, WDIM=512, K=3
// y = lrelu( demod * conv3x3(x*s, cw/48) + nw*noise + bias )
//
// Round 4: conv keeps W out of LDS (global fragment-major A-frags, L2-hot),
// X staged via linear global_load_lds into double-buffered LDS with the
// bank-swizzle baked into xt's global layout. One barrier per cin-chunk.

typedef __attribute__((ext_vector_type(8))) short bf16x8;
typedef __attribute__((ext_vector_type(4))) float f32x4;

#define INV_SQRT_WDIM 0.04419417382415922f  // 1/sqrt(512)

__device__ __forceinline__ void gload_lds16(const void* g, void* l) {
  __builtin_amdgcn_global_load_lds(
      (const __attribute__((address_space(1))) void*)g,
      (__attribute__((address_space(3))) void*)l, 16, 0, 0);
}

// K1: s[b][c] = dot(w[b,:], sw[c,:]) / sqrt(512) + sb[c]
// one block per c, coalesced float2 reads, shfl+LDS reduce for all 8 b.
__global__ __launch_bounds__(256)
void style2_kernel(const float* __restrict__ w, const float* __restrict__ sw,
                   const float* __restrict__ sb, float* __restrict__ s) {
  const int c = blockIdx.x, t = threadIdx.x;
  const int lane = t & 63, wvi = t >> 6;
  const float2 swv = *(const float2*)&sw[c * 512 + t * 2];
  __shared__ float red[4][8];
  float acc[8];
#pragma unroll
  for (int b = 0; b < 8; ++b) {
    const float2 wv2 = *(const float2*)&w[b * 512 + t * 2];
    acc[b] = swv.x * wv2.x + swv.y * wv2.y;
  }
#pragma unroll
  for (int b = 0; b < 8; ++b)
#pragma unroll
    for (int off = 32; off > 0; off >>= 1) acc[b] += __shfl_down(acc[b], off);
  if (lane == 0)
#pragma unroll
    for (int b = 0; b < 8; ++b) red[wvi][b] = acc[b];
  __syncthreads();
  if (t < 8) {
    float tot = red[0][t] + red[1][t] + red[2][t] + red[3][t];
    s[t * 256 + c] = tot * INV_SQRT_WDIM + sb[c];
  }
}

// K2: fused weight transform + demod.
// wt2 layout (elements): t*65536 + cc*8192 + o16*512 + kg*128 + row*8 + e
//   where o = o16*16+row, i = cc*32 + kg*8 + e   (A-frag coalesced per wave)
// demod[b][o] = rsqrt( (1/2304) * sum_i w2[o,i] * s[b,i]^2 + 1e-8 )
__global__ __launch_bounds__(256)
void wdm_kernel(const float* __restrict__ cw, const float* __restrict__ s,
                __hip_bfloat16* __restrict__ wt2, float* __restrict__ demod) {
  const int o = blockIdx.x, i = threadIdx.x;
  const int lane = i & 63, wvi = i >> 6;
  float v[9];
  float w2 = 0.f;
#pragma unroll
  for (int t = 0; t < 9; ++t) {
    v[t] = cw[(o * 256 + i) * 9 + t];
    w2 += v[t] * v[t];
  }
  const int wbase = (i >> 5) * 8192 + (o >> 4) * 512 + ((i >> 3) & 3) * 128 +
                    (o & 15) * 8 + (i & 7);
#pragma unroll
  for (int t = 0; t < 9; ++t)
    wt2[t * 65536 + wbase] = __float2bfloat16(v[t] * (1.0f / 48.0f));
  __shared__ float red[4][8];
  float pv[8];
#pragma unroll
  for (int b = 0; b < 8; ++b) {
    const float sv = s[b * 256 + i];
    pv[b] = w2 * sv * sv;
  }
#pragma unroll
  for (int b = 0; b < 8; ++b)
#pragma unroll
    for (int off = 32; off > 0; off >>= 1) pv[b] += __shfl_down(pv[b], off);
  if (lane == 0)
#pragma unroll
    for (int b = 0; b < 8; ++b) red[wvi][b] = pv[b];
  __syncthreads();
  if (i < 8) {
    float tot = red[0][i] + red[1][i] + red[2][i] + red[3][i];
    demod[i * 256 + o] = rsqrtf(tot * (1.0f / 2304.0f) + 1e-8f);
  }
}

// K4: xt[b][h][w][cin] = bf16( x[b][cin][h][w] * s[b][cin] ), NHWC with the
// conv bank-swizzle baked in: group G=cin>>3 stored at chunk cc=G>>2,
// slot (G&3)^((w>>1)&3). Conv then stages LINEAR and reads swizzled.
__global__ __launch_bounds__(256)
void xmod_kernel(const float* __restrict__ x, const float* __restrict__ s,
                 __hip_bfloat16* __restrict__ xt) {
  const int h = blockIdx.x;
  const int b = blockIdx.y;
  __shared__ __hip_bfloat16 tile[256 * 66];
  const int t = threadIdx.x;
  const int wl4 = (t & 15) * 4;
#pragma unroll 4
  for (int p = 0; p < 16; ++p) {
    const int i = p * 16 + (t >> 4);
    const float4 v = *(const float4*)&x[((b * 256 + i) * 64 + h) * 64 + wl4];
    const float sv = s[b * 256 + i];
    const int wsw = wl4 ^ (((i >> 3) & 7) << 3);
    unsigned lo = ((unsigned)__bfloat16_as_ushort(__float2bfloat16(v.y * sv)) << 16) |
                  (unsigned)__bfloat16_as_ushort(__float2bfloat16(v.x * sv));
    unsigned hi = ((unsigned)__bfloat16_as_ushort(__float2bfloat16(v.w * sv)) << 16) |
                  (unsigned)__bfloat16_as_ushort(__float2bfloat16(v.z * sv));
    *(unsigned*)&tile[i * 66 + wsw] = lo;
    *(unsigned*)&tile[i * 66 + wsw + 2] = hi;
  }
  __syncthreads();
#pragma unroll 2
  for (int p = 0; p < 8; ++p) {
    const int w = p * 8 + (t >> 5);
    const int c = t & 31;  // group G = c: cin = c*8 + j
    ushort out8[8];
#pragma unroll
    for (int j = 0; j < 8; ++j) {
      const int i = c * 8 + j;
      const int wsw = w ^ (((i >> 3) & 7) << 3);
      out8[j] = __bfloat16_as_ushort(tile[i * 66 + wsw]);
    }
    const int slot = (c & 3) ^ ((w >> 1) & 3);
    *(uint4*)&xt[((b * 64 + h) * 64 + w) * 256 + (c >> 2) * 32 + slot * 8] =
        *(uint4*)out8;
  }
}

// K5: conv as 9 shifted GEMMs, mfma_f32_16x16x32_bf16.
// Block: 64 oc x (4 rows x 64 w), b fixed, 4 waves (wave = one h row).
// X: double-buffered xlds[2][6][64][32] via linear global_load_lds (xt is
//    pre-swizzled in memory); B-reads use slot=(lane>>4)^((wc>>1)&3): <=2-way.
// W: A-frags straight from global wt2 (fragment-major, 1KB/wave coalesced, L2-hot).
__global__ __launch_bounds__(256, 3)
void conv_mfma_kernel(const __hip_bfloat16* __restrict__ xt,
                      const __hip_bfloat16* __restrict__ wt2,
                      const float* __restrict__ demod,
                      const float* __restrict__ noise,
                      const float* __restrict__ nw,
                      const float* __restrict__ bias,
                      const __hip_bfloat16* __restrict__ zbuf,
                      float* __restrict__ out) {
  __shared__ __hip_bfloat16 xlds[2][12288] __attribute__((aligned(16)));

  const int tid = threadIdx.x;
  const int lane = tid & 63;
  const int wv = tid >> 6;

  const int h0 = blockIdx.x * 4;   // 16 spatial tiles
  const int oc0 = blockIdx.y * 64; // 4 oc tiles
  const int b = blockIdx.z;        // 8 batches

  // A-frag per-lane offset within a (t,cc,o16) 1KB chunk
  const int aoff = (lane >> 4) * 128 + (lane & 15) * 8;
  const int o16b = oc0 >> 4;

  // B-frag offsets: slot recovers original k-group lane>>4 from swizzled slots
  int boff[4][3];
  bool bok[4][3];
#pragma unroll
  for (int q = 0; q < 4; ++q)
#pragma unroll
    for (int tj = 0; tj < 3; ++tj) {
      int wx = q * 16 + (lane & 15) + tj - 1;
      bool ok = (unsigned)wx < 64u;
      int wc = ok ? wx : 0;
      int slot = (lane >> 4) ^ ((wc >> 1) & 3);
      boff[q][tj] = wc * 32 + slot * 8;
      bok[q][tj] = ok;
    }

  const f32x4 zero4 = {0.f, 0.f, 0.f, 0.f};
  const bf16x8 zerov = {0, 0, 0, 0, 0, 0, 0, 0};
  f32x4 acc[4][4];
#pragma unroll
  for (int m = 0; m < 4; ++m)
#pragma unroll
    for (int q = 0; q < 4; ++q) acc[m][q] = zero4;

  // stage chunk scc into buffer buf: 24 x 1KB wave-issues (6 per wave), linear
  auto stage = [&](int buf, int scc) {
#pragma unroll
    for (int k = 0; k < 6; ++k) {
      const int ch = wv * 6 + k;          // 0..23
      const int r = ch >> 2;              // halo row 0..5
      const int wseg = ch & 3;            // 16-col segment
      const int gr = h0 - 1 + r;
      const __hip_bfloat16* src =
          ((unsigned)gr < 64u)
              ? xt + ((b * 64 + gr) * 64 + wseg * 16 + (lane >> 2)) * 256 +
                    scc * 32 + (lane & 3) * 8
              : zbuf;
      gload_lds16(src, &xlds[buf][ch * 512]);
    }
  };

  stage(0, 0);
  __syncthreads();

  for (int cc = 0; cc < 8; ++cc) {
    const int cur = cc & 1;
    if (cc < 7) stage(cur ^ 1, cc + 1);
#pragma unroll
    for (int ti = 0; ti < 3; ++ti) {
#pragma unroll
      for (int tj = 0; tj < 3; ++tj) {
        const int t = ti * 3 + tj;
        bf16x8 av[4];
#pragma unroll
        for (int m = 0; m < 4; ++m)
          av[m] = *(const bf16x8*)&wt2[t * 65536 + cc * 8192 +
                                       (o16b + m) * 512 + aoff];
#pragma unroll
        for (int q = 0; q < 4; ++q) {
          bf16x8 bv = *(const bf16x8*)&xlds[cur][(wv + ti) * 2048 + boff[q][tj]];
          if (!bok[q][tj]) bv = zerov;
#pragma unroll
          for (int m = 0; m < 4; ++m)
            acc[m][q] = __builtin_amdgcn_mfma_f32_16x16x32_bf16(av[m], bv,
                                                                acc[m][q], 0, 0, 0);
        }
      }
    }
    __syncthreads();  // implicit vmcnt(0)+lgkmcnt(0): stage done, reads done
  }

  // epilogue: C/D layout col=lane&15 (w), row=4*(lane>>4)+reg (oc offset)
  const int hrow = h0 + wv;
  float nzv[4];
#pragma unroll
  for (int q = 0; q < 4; ++q)
    nzv[q] = noise[b * 4096 + hrow * 64 + q * 16 + (lane & 15)];
#pragma unroll
  for (int m = 0; m < 4; ++m) {
#pragma unroll
    for (int reg = 0; reg < 4; ++reg) {
      const int oc = oc0 + m * 16 + (lane >> 4) * 4 + reg;
      const float dm = demod[b * 256 + oc];
      const float nwv = nw[oc];
      const float bvv = bias[oc];
#pragma unroll
      for (int q = 0; q < 4; ++q) {
        float v = acc[m][q][reg] * dm + nwv * nzv[q] + bvv;
        v = (v >= 0.f) ? v : 0.2f * v;
        out[((b * 256 + oc) * 64 + hrow) * 64 + q * 16 + (lane & 15)] = v;
      }
    }
  }
}

extern "C" void kernel_launch(void* const* d_in, const int* in_sizes, int n_in,
                              void* d_out, int out_size, void* d_ws, size_t ws_size,
                              hipStream_t stream) {
  const float* x     = (const float*)d_in[0];  // [8,256,64,64]
  const float* w     = (const float*)d_in[1];  // [8,512]
  const float* noise = (const float*)d_in[2];  // [8,1,64,64]
  const float* sw    = (const float*)d_in[3];  // [256,512]
  const float* sb    = (const float*)d_in[4];  // [256]
  const float* cw    = (const float*)d_in[5];  // [256,256,3,3]
  const float* nw    = (const float*)d_in[6];  // [256]
  const float* bias  = (const float*)d_in[7];  // [256]
  float* out = (float*)d_out;                  // [8,256,64,64]

  char* ws = (char*)d_ws;
  float* s            = (float*)(ws);            // 8 KB
  float* demod        = (float*)(ws + 8192);     // 8 KB
  __hip_bfloat16* zbuf = (__hip_bfloat16*)(ws + 16384);   // 1 KB zeros
  __hip_bfloat16* wt2 = (__hip_bfloat16*)(ws + 17408);    // 1.18 MB
  __hip_bfloat16* xt  = (__hip_bfloat16*)(ws + 1197056);  // 16.8 MB

  hipMemsetAsync(zbuf, 0, 1024, stream);
  style2_kernel<<<256, 256, 0, stream>>>(w, sw, sb, s);
  wdm_kernel<<<256, 256, 0, stream>>>(cw, s, wt2, demod);
  xmod_kernel<<<dim3(64, 8), 256, 0, stream>>>(x, s, xt);
  conv_mfma_kernel<<<dim3(16, 4, 8), 256, 0, stream>>>(
      xt, wt2, demod, noise, nw, bias, zbuf, out);
}

// Round 8
// 143.653 us; speedup vs baseline: 1.1366x; 1.0720x over previous
//
#include <hip/hip_runtime.h>
#include <hip/hip_bf16.h>

// SynthesisLayer: B=8, CIN=256, COUT=256, H=W=64, WDIM=512, K=3
// y = lrelu( demod * conv3x3(x*s, cw/48) + nw*noise + bias )
//
// Round 5-8: conv A-frags via ring-3 register prefetch from global (L2-hot
// wt2), B via linear global_load_lds double-buffer (0 bank conflicts, r4).

typedef __attribute__((ext_vector_type(8))) short bf16x8;
typedef __attribute__((ext_vector_type(4))) float f32x4;

#define INV_SQRT_WDIM 0.04419417382415922f  // 1/sqrt(512)

__device__ __forceinline__ void gload_lds16(const void* g, void* l) {
  __builtin_amdgcn_global_load_lds(
      (const __attribute__((address_space(1))) void*)g,
      (__attribute__((address_space(3))) void*)l, 16, 0, 0);
}

// K1: s[b][c] = dot(w[b,:], sw[c,:]) / sqrt(512) + sb[c]; block 0 zeroes zbuf.
__global__ __launch_bounds__(256)
void style2_kernel(const float* __restrict__ w, const float* __restrict__ sw,
                   const float* __restrict__ sb, float* __restrict__ s,
                   unsigned* __restrict__ zbuf) {
  const int c = blockIdx.x, t = threadIdx.x;
  const int lane = t & 63, wvi = t >> 6;
  if (c == 0) zbuf[t] = 0u;  // 1 KB zeros for conv halo redirect
  const float2 swv = *(const float2*)&sw[c * 512 + t * 2];
  __shared__ float red[4][8];
  float acc[8];
#pragma unroll
  for (int b = 0; b < 8; ++b) {
    const float2 wv2 = *(const float2*)&w[b * 512 + t * 2];
    acc[b] = swv.x * wv2.x + swv.y * wv2.y;
  }
#pragma unroll
  for (int b = 0; b < 8; ++b)
#pragma unroll
    for (int off = 32; off > 0; off >>= 1) acc[b] += __shfl_down(acc[b], off);
  if (lane == 0)
#pragma unroll
    for (int b = 0; b < 8; ++b) red[wvi][b] = acc[b];
  __syncthreads();
  if (t < 8) {
    float tot = red[0][t] + red[1][t] + red[2][t] + red[3][t];
    s[t * 256 + c] = tot * INV_SQRT_WDIM + sb[c];
  }
}

// K2: fused weight transform + demod.
// wt2 layout (elements): t*65536 + cc*8192 + o16*512 + kg*128 + row*8 + e
//   where o = o16*16+row, i = cc*32 + kg*8 + e   (A-frag coalesced per wave)
__global__ __launch_bounds__(256)
void wdm_kernel(const float* __restrict__ cw, const float* __restrict__ s,
                __hip_bfloat16* __restrict__ wt2, float* __restrict__ demod) {
  const int o = blockIdx.x, i = threadIdx.x;
  const int lane = i & 63, wvi = i >> 6;
  float v[9];
  float w2 = 0.f;
#pragma unroll
  for (int t = 0; t < 9; ++t) {
    v[t] = cw[(o * 256 + i) * 9 + t];
    w2 += v[t] * v[t];
  }
  const int wbase = (i >> 5) * 8192 + (o >> 4) * 512 + ((i >> 3) & 3) * 128 +
                    (o & 15) * 8 + (i & 7);
#pragma unroll
  for (int t = 0; t < 9; ++t)
    wt2[t * 65536 + wbase] = __float2bfloat16(v[t] * (1.0f / 48.0f));
  __shared__ float red[4][8];
  float pv[8];
#pragma unroll
  for (int b = 0; b < 8; ++b) {
    const float sv = s[b * 256 + i];
    pv[b] = w2 * sv * sv;
  }
#pragma unroll
  for (int b = 0; b < 8; ++b)
#pragma unroll
    for (int off = 32; off > 0; off >>= 1) pv[b] += __shfl_down(pv[b], off);
  if (lane == 0)
#pragma unroll
    for (int b = 0; b < 8; ++b) red[wvi][b] = pv[b];
  __syncthreads();
  if (i < 8) {
    float tot = red[0][i] + red[1][i] + red[2][i] + red[3][i];
    demod[i * 256 + o] = rsqrtf(tot * (1.0f / 2304.0f) + 1e-8f);
  }
}

// K4: xt[b][h][w][cin] = bf16( x[b][cin][h][w] * s[b][cin] ), NHWC with the
// conv bank-swizzle baked in: group G=cin>>3 stored at chunk cc=G>>2,
// slot (G&3)^((w>>1)&3). Conv then stages LINEAR and reads swizzled.
__global__ __launch_bounds__(256)
void xmod_kernel(const float* __restrict__ x, const float* __restrict__ s,
                 __hip_bfloat16* __restrict__ xt) {
  const int h = blockIdx.x;
  const int b = blockIdx.y;
  __shared__ __hip_bfloat16 tile[256 * 66];
  const int t = threadIdx.x;
  const int wl4 = (t & 15) * 4;
#pragma unroll 4
  for (int p = 0; p < 16; ++p) {
    const int i = p * 16 + (t >> 4);
    const float4 v = *(const float4*)&x[((b * 256 + i) * 64 + h) * 64 + wl4];
    const float sv = s[b * 256 + i];
    const int wsw = wl4 ^ (((i >> 3) & 7) << 3);
    unsigned lo = ((unsigned)__bfloat16_as_ushort(__float2bfloat16(v.y * sv)) << 16) |
                  (unsigned)__bfloat16_as_ushort(__float2bfloat16(v.x * sv));
    unsigned hi = ((unsigned)__bfloat16_as_ushort(__float2bfloat16(v.w * sv)) << 16) |
                  (unsigned)__bfloat16_as_ushort(__float2bfloat16(v.z * sv));
    *(unsigned*)&tile[i * 66 + wsw] = lo;
    *(unsigned*)&tile[i * 66 + wsw + 2] = hi;
  }
  __syncthreads();
#pragma unroll 2
  for (int p = 0; p < 8; ++p) {
    const int w = p * 8 + (t >> 5);
    const int c = t & 31;  // group G = c: cin = c*8 + j
    ushort out8[8];
#pragma unroll
    for (int j = 0; j < 8; ++j) {
      const int i = c * 8 + j;
      const int wsw = w ^ (((i >> 3) & 7) << 3);
      out8[j] = __bfloat16_as_ushort(tile[i * 66 + wsw]);
    }
    const int slot = (c & 3) ^ ((w >> 1) & 3);
    *(uint4*)&xt[((b * 64 + h) * 64 + w) * 256 + (c >> 2) * 32 + slot * 8] =
        *(uint4*)out8;
  }
}

// K5: conv as 9 shifted GEMMs, mfma_f32_16x16x32_bf16.
// Block: 64 oc x (4 rows x 64 w), b fixed, 4 waves (wave = one h row).
// X: double-buffered xlds[2][6][64][32] via linear global_load_lds (xt is
//    pre-swizzled in memory); B-reads use slot=(lane>>4)^((wc>>1)&3): <=2-way.
// W: A-frags from global wt2 via ring-3 register prefetch (use slot t%3, then
//    reload it with tap t+3; 9%3==0 makes the ring phase chunk-invariant).
__global__ __launch_bounds__(256, 2)
void conv_mfma_kernel(const __hip_bfloat16* __restrict__ xt,
                      const __hip_bfloat16* __restrict__ wt2,
                      const float* __restrict__ demod,
                      const float* __restrict__ noise,
                      const float* __restrict__ nw,
                      const float* __restrict__ bias,
                      const __hip_bfloat16* __restrict__ zbuf,
                      float* __restrict__ out) {
  __shared__ __hip_bfloat16 xlds[2][12288] __attribute__((aligned(16)));

  const int tid = threadIdx.x;
  const int lane = tid & 63;
  const int wv = tid >> 6;

  const int h0 = blockIdx.x * 4;   // 16 spatial tiles
  const int oc0 = blockIdx.y * 64; // 4 oc tiles
  const int b = blockIdx.z;        // 8 batches

  // A-frag per-lane base inside wt2 (add t*65536 + cc*8192 + m*512)
  const __hip_bfloat16* wbase =
      wt2 + (oc0 >> 4) * 512 + (lane >> 4) * 128 + (lane & 15) * 8;

  // B-frag offsets: slot recovers original k-group lane>>4 from swizzled slots
  int boff[4][3];
  bool bok[4][3];
#pragma unroll
  for (int q = 0; q < 4; ++q)
#pragma unroll
    for (int tj = 0; tj < 3; ++tj) {
      int wx = q * 16 + (lane & 15) + tj - 1;
      bool ok = (unsigned)wx < 64u;
      int wc = ok ? wx : 0;
      int slot = (lane >> 4) ^ ((wc >> 1) & 3);
      boff[q][tj] = wc * 32 + slot * 8;
      bok[q][tj] = ok;
    }

  const f32x4 zero4 = {0.f, 0.f, 0.f, 0.f};
  const bf16x8 zerov = {0, 0, 0, 0, 0, 0, 0, 0};
  f32x4 acc[4][4];
#pragma unroll
  for (int m = 0; m < 4; ++m)
#pragma unroll
    for (int q = 0; q < 4; ++q) acc[m][q] = zero4;

  // stage chunk scc into buffer buf: 24 x 1KB wave-issues (6 per wave), linear
  auto stage = [&](int buf, int scc) {
#pragma unroll
    for (int k = 0; k < 6; ++k) {
      const int ch = wv * 6 + k;          // 0..23
      const int r = ch >> 2;              // halo row 0..5
      const int wseg = ch & 3;            // 16-col segment
      const int gr = h0 - 1 + r;
      const __hip_bfloat16* src =
          ((unsigned)gr < 64u)
              ? xt + ((b * 64 + gr) * 64 + wseg * 16 + (lane >> 2)) * 256 +
                    scc * 32 + (lane & 3) * 8
              : zbuf;
      gload_lds16(src, &xlds[buf][ch * 512]);
    }
  };

  // A ring prefetch: slots 0..2 <- taps 0..2 of chunk 0
  bf16x8 avp[3][4];
  stage(0, 0);
#pragma unroll
  for (int pt = 0; pt < 3; ++pt)
#pragma unroll
    for (int m = 0; m < 4; ++m)
      avp[pt][m] = *(const bf16x8*)&wbase[pt * 65536 + m * 512];
  __syncthreads();

  for (int cc = 0; cc < 8; ++cc) {
    const int cur = cc & 1;
    const __hip_bfloat16* wcc = wbase + cc * 8192;
    if (cc < 7) stage(cur ^ 1, cc + 1);
#pragma unroll
    for (int ti = 0; ti < 3; ++ti) {
#pragma unroll
      for (int tj = 0; tj < 3; ++tj) {
        const int t = ti * 3 + tj;
        const int sl = t % 3;  // compile-time under unroll
#pragma unroll
        for (int q = 0; q < 4; ++q) {
          bf16x8 bv = *(const bf16x8*)&xlds[cur][(wv + ti) * 2048 + boff[q][tj]];
          if (!bok[q][tj]) bv = zerov;
#pragma unroll
          for (int m = 0; m < 4; ++m)
            acc[m][q] = __builtin_amdgcn_mfma_f32_16x16x32_bf16(avp[sl][m], bv,
                                                                acc[m][q], 0, 0, 0);
        }
        // reload this ring slot with tap t+3 (next chunk's taps 0..2 when t>=6;
        // cc==7 overreach stays inside wt2 and is never used)
        const int nt = (t + 3 < 9) ? (t + 3) : (t - 6);
        const int ncc = (t + 3 < 9) ? 0 : 8192;
#pragma unroll
        for (int m = 0; m < 4; ++m)
          avp[sl][m] = *(const bf16x8*)&wcc[nt * 65536 + ncc + m * 512];
      }
    }
    __syncthreads();  // stage done + LDS reads done; next buffer ready
  }

  // epilogue: C/D layout col=lane&15 (w), row=4*(lane>>4)+reg (oc offset)
  const int hrow = h0 + wv;
  float nzv[4];
#pragma unroll
  for (int q = 0; q < 4; ++q)
    nzv[q] = noise[b * 4096 + hrow * 64 + q * 16 + (lane & 15)];
#pragma unroll
  for (int m = 0; m < 4; ++m) {
#pragma unroll
    for (int reg = 0; reg < 4; ++reg) {
      const int oc = oc0 + m * 16 + (lane >> 4) * 4 + reg;
      const float dm = demod[b * 256 + oc];
      const float nwv = nw[oc];
      const float bvv = bias[oc];
#pragma unroll
      for (int q = 0; q < 4; ++q) {
        float v = acc[m][q][reg] * dm + nwv * nzv[q] + bvv;
        v = (v >= 0.f) ? v : 0.2f * v;
        out[((b * 256 + oc) * 64 + hrow) * 64 + q * 16 + (lane & 15)] = v;
      }
    }
  }
}

extern "C" void kernel_launch(void* const* d_in, const int* in_sizes, int n_in,
                              void* d_out, int out_size, void* d_ws, size_t ws_size,
                              hipStream_t stream) {
  const float* x     = (const float*)d_in[0];  // [8,256,64,64]
  const float* w     = (const float*)d_in[1];  // [8,512]
  const float* noise = (const float*)d_in[2];  // [8,1,64,64]
  const float* sw    = (const float*)d_in[3];  // [256,512]
  const float* sb    = (const float*)d_in[4];  // [256]
  const float* cw    = (const float*)d_in[5];  // [256,256,3,3]
  const float* nw    = (const float*)d_in[6];  // [256]
  const float* bias  = (const float*)d_in[7];  // [256]
  float* out = (float*)d_out;                  // [8,256,64,64]

  char* ws = (char*)d_ws;
  float* s            = (float*)(ws);            // 8 KB
  float* demod        = (float*)(ws + 8192);     // 8 KB
  unsigned* zbuf      = (unsigned*)(ws + 16384); // 1 KB zeros
  __hip_bfloat16* wt2 = (__hip_bfloat16*)(ws + 17408);    // 1.18 MB
  __hip_bfloat16* xt  = (__hip_bfloat16*)(ws + 1197056);  // 16.8 MB

  style2_kernel<<<256, 256, 0, stream>>>(w, sw, sb, s, zbuf);
  wdm_kernel<<<256, 256, 0, stream>>>(cw, s, wt2, demod);
  xmod_kernel<<<dim3(64, 8), 256, 0, stream>>>(x, s, xt);
  conv_mfma_kernel<<<dim3(16, 4, 8), 256, 0, stream>>>(
      xt, wt2, demod, noise, nw, bias, (const __hip_bfloat16*)zbuf, out);
}

// Round 12
// 134.928 us; speedup vs baseline: 1.2101x; 1.0647x over previous
//
#include <hip/hip_runtime.h>
#include <hip/hip_bf16.h>

// SynthesisLayer: B=8, CIN=256, COUT=256, H=W=64, WDIM=512, K=3
// y = lrelu( demod * conv3x3(x*s, cw/48) + nw*noise + bias )
//
// Round 9-12: 512-thread conv blocks (8 h-rows); W staged to LDS fragment-major
// (conflict-free) + X pre-swizzled, both double-buffered via linear
// global_load_lds; one barrier per cin-chunk. W L2 traffic 604MB -> 75MB.

typedef __attribute__((ext_vector_type(8))) short bf16x8;
typedef __attribute__((ext_vector_type(4))) float f32x4;

#define INV_SQRT_WDIM 0.04419417382415922f  // 1/sqrt(512)

__device__ __forceinline__ void gload_lds16(const void* g, void* l) {
  __builtin_amdgcn_global_load_lds(
      (const __attribute__((address_space(1))) void*)g,
      (__attribute__((address_space(3))) void*)l, 16, 0, 0);
}

// K1: s[b][c] = dot(w[b,:], sw[c,:]) / sqrt(512) + sb[c]; block 0 zeroes zbuf.
__global__ __launch_bounds__(256)
void style2_kernel(const float* __restrict__ w, const float* __restrict__ sw,
                   const float* __restrict__ sb, float* __restrict__ s,
                   unsigned* __restrict__ zbuf) {
  const int c = blockIdx.x, t = threadIdx.x;
  const int lane = t & 63, wvi = t >> 6;
  if (c == 0) zbuf[t] = 0u;  // 1 KB zeros for conv halo redirect
  const float2 swv = *(const float2*)&sw[c * 512 + t * 2];
  __shared__ float red[4][8];
  float acc[8];
#pragma unroll
  for (int b = 0; b < 8; ++b) {
    const float2 wv2 = *(const float2*)&w[b * 512 + t * 2];
    acc[b] = swv.x * wv2.x + swv.y * wv2.y;
  }
#pragma unroll
  for (int b = 0; b < 8; ++b)
#pragma unroll
    for (int off = 32; off > 0; off >>= 1) acc[b] += __shfl_down(acc[b], off);
  if (lane == 0)
#pragma unroll
    for (int b = 0; b < 8; ++b) red[wvi][b] = acc[b];
  __syncthreads();
  if (t < 8) {
    float tot = red[0][t] + red[1][t] + red[2][t] + red[3][t];
    s[t * 256 + c] = tot * INV_SQRT_WDIM + sb[c];
  }
}

// K2: fused weight transform + demod.
// wt2 layout (elements): t*65536 + cc*8192 + o16*512 + kg*128 + row*8 + e
//   where o = o16*16+row, i = cc*32 + kg*8 + e   (A-frag coalesced per wave)
__global__ __launch_bounds__(256)
void wdm_kernel(const float* __restrict__ cw, const float* __restrict__ s,
                __hip_bfloat16* __restrict__ wt2, float* __restrict__ demod) {
  const int o = blockIdx.x, i = threadIdx.x;
  const int lane = i & 63, wvi = i >> 6;
  float v[9];
  float w2 = 0.f;
#pragma unroll
  for (int t = 0; t < 9; ++t) {
    v[t] = cw[(o * 256 + i) * 9 + t];
    w2 += v[t] * v[t];
  }
  const int wbase = (i >> 5) * 8192 + (o >> 4) * 512 + ((i >> 3) & 3) * 128 +
                    (o & 15) * 8 + (i & 7);
#pragma unroll
  for (int t = 0; t < 9; ++t)
    wt2[t * 65536 + wbase] = __float2bfloat16(v[t] * (1.0f / 48.0f));
  __shared__ float red[4][8];
  float pv[8];
#pragma unroll
  for (int b = 0; b < 8; ++b) {
    const float sv = s[b * 256 + i];
    pv[b] = w2 * sv * sv;
  }
#pragma unroll
  for (int b = 0; b < 8; ++b)
#pragma unroll
    for (int off = 32; off > 0; off >>= 1) pv[b] += __shfl_down(pv[b], off);
  if (lane == 0)
#pragma unroll
    for (int b = 0; b < 8; ++b) red[wvi][b] = pv[b];
  __syncthreads();
  if (i < 8) {
    float tot = red[0][i] + red[1][i] + red[2][i] + red[3][i];
    demod[i * 256 + o] = rsqrtf(tot * (1.0f / 2304.0f) + 1e-8f);
  }
}

// K4: xt[b][h][w][cin] = bf16( x[b][cin][h][w] * s[b][cin] ), NHWC with the
// conv bank-swizzle baked in: group G=cin>>3 stored at chunk cc=G>>2,
// slot (G&3)^((w>>1)&3). Conv then stages LINEAR and reads swizzled.
__global__ __launch_bounds__(256)
void xmod_kernel(const float* __restrict__ x, const float* __restrict__ s,
                 __hip_bfloat16* __restrict__ xt) {
  const int h = blockIdx.x;
  const int b = blockIdx.y;
  __shared__ __hip_bfloat16 tile[256 * 66];
  const int t = threadIdx.x;
  const int wl4 = (t & 15) * 4;
#pragma unroll 4
  for (int p = 0; p < 16; ++p) {
    const int i = p * 16 + (t >> 4);
    const float4 v = *(const float4*)&x[((b * 256 + i) * 64 + h) * 64 + wl4];
    const float sv = s[b * 256 + i];
    const int wsw = wl4 ^ (((i >> 3) & 7) << 3);
    unsigned lo = ((unsigned)__bfloat16_as_ushort(__float2bfloat16(v.y * sv)) << 16) |
                  (unsigned)__bfloat16_as_ushort(__float2bfloat16(v.x * sv));
    unsigned hi = ((unsigned)__bfloat16_as_ushort(__float2bfloat16(v.w * sv)) << 16) |
                  (unsigned)__bfloat16_as_ushort(__float2bfloat16(v.z * sv));
    *(unsigned*)&tile[i * 66 + wsw] = lo;
    *(unsigned*)&tile[i * 66 + wsw + 2] = hi;
  }
  __syncthreads();
#pragma unroll 2
  for (int p = 0; p < 8; ++p) {
    const int w = p * 8 + (t >> 5);
    const int c = t & 31;  // group G = c: cin = c*8 + j
    ushort out8[8];
#pragma unroll
    for (int j = 0; j < 8; ++j) {
      const int i = c * 8 + j;
      const int wsw = w ^ (((i >> 3) & 7) << 3);
      out8[j] = __bfloat16_as_ushort(tile[i * 66 + wsw]);
    }
    const int slot = (c & 3) ^ ((w >> 1) & 3);
    *(uint4*)&xt[((b * 64 + h) * 64 + w) * 256 + (c >> 2) * 32 + slot * 8] =
        *(uint4*)out8;
  }
}

// K5: conv as 9 shifted GEMMs, mfma_f32_16x16x32_bf16.
// Block: 512 threads = 8 waves; wave wv owns row h0+wv, 64 oc, 64 w.
// Per chunk buffer (77824 B): X [10 rows][64 w][32 cin] pre-swizzled (40960 B)
//   then W fragment-major [9 taps][4 o16][512] (36864 B). Double-buffered.
__global__ __launch_bounds__(512, 2)
void conv_mfma_kernel(const __hip_bfloat16* __restrict__ xt,
                      const __hip_bfloat16* __restrict__ wt2,
                      const float* __restrict__ demod,
                      const float* __restrict__ noise,
                      const float* __restrict__ nw,
                      const float* __restrict__ bias,
                      const __hip_bfloat16* __restrict__ zbuf,
                      float* __restrict__ out) {
  extern __shared__ __hip_bfloat16 smem[];  // 2 * 38912 elements

  const int tid = threadIdx.x;
  const int lane = tid & 63;
  const int wv = tid >> 6;  // 0..7

  const int h0 = blockIdx.x * 8;   // 8 spatial tiles
  const int oc0 = blockIdx.y * 64; // 4 oc tiles
  const int b = blockIdx.z;        // 8 batches

  // A-frag per-lane offset inside a 512-elem o16-block: kg*128 + row*8
  const int aoff = (lane >> 4) * 128 + (lane & 15) * 8;

  // B-frag offsets: slot recovers original k-group lane>>4 from swizzled slots
  int boff[4][3];
  bool bok[4][3];
#pragma unroll
  for (int q = 0; q < 4; ++q)
#pragma unroll
    for (int tj = 0; tj < 3; ++tj) {
      int wx = q * 16 + (lane & 15) + tj - 1;
      bool ok = (unsigned)wx < 64u;
      int wc = ok ? wx : 0;
      int slot = (lane >> 4) ^ ((wc >> 1) & 3);
      boff[q][tj] = wc * 32 + slot * 8;
      bok[q][tj] = ok;
    }

  const f32x4 zero4 = {0.f, 0.f, 0.f, 0.f};
  const bf16x8 zerov = {0, 0, 0, 0, 0, 0, 0, 0};
  f32x4 acc[4][4];
#pragma unroll
  for (int m = 0; m < 4; ++m)
#pragma unroll
    for (int q = 0; q < 4; ++q) acc[m][q] = zero4;

  // stage chunk scc into buffer buf (X: 40 x 1KB, W: 36 x 1KB wave-issues)
  auto stage = [&](__hip_bfloat16* buf, int scc) {
#pragma unroll
    for (int k = 0; k < 5; ++k) {
      const int ch = wv * 5 + k;  // 0..39: r = ch>>2 (10 rows), wseg = ch&3
      const int r = ch >> 2;
      const int wseg = ch & 3;
      const int gr = h0 - 1 + r;
      const __hip_bfloat16* src =
          ((unsigned)gr < 64u)
              ? xt + ((b * 64 + gr) * 64 + wseg * 16 + (lane >> 2)) * 256 +
                    scc * 32 + (lane & 3) * 8
              : zbuf;
      gload_lds16(src, buf + ch * 512);
    }
#pragma unroll
    for (int k = 0; k < 5; ++k) {
      const int j = wv + 8 * k;  // 0..39, use j<36: t = j>>2, o16-sub = j&3
      if (j < 36) {
        const __hip_bfloat16* src = wt2 + (j >> 2) * 65536 + scc * 8192 +
                                    (oc0 >> 4) * 512 + (j & 3) * 512 + lane * 8;
        gload_lds16(src, buf + 20480 + j * 512);
      }
    }
  };

  stage(smem, 0);
  __syncthreads();

  for (int cc = 0; cc < 8; ++cc) {
    __hip_bfloat16* cbuf = smem + (cc & 1) * 38912;
    __hip_bfloat16* nbuf = smem + ((cc & 1) ^ 1) * 38912;
    if (cc < 7) stage(nbuf, cc + 1);
    const __hip_bfloat16* wb = cbuf + 20480;
#pragma unroll
    for (int ti = 0; ti < 3; ++ti) {
#pragma unroll
      for (int tj = 0; tj < 3; ++tj) {
        const int t = ti * 3 + tj;
        bf16x8 av[4];
#pragma unroll
        for (int m = 0; m < 4; ++m)
          av[m] = *(const bf16x8*)&wb[t * 2048 + m * 512 + aoff];
#pragma unroll
        for (int q = 0; q < 4; ++q) {
          bf16x8 bv = *(const bf16x8*)&cbuf[(wv + ti) * 2048 + boff[q][tj]];
          if (!bok[q][tj]) bv = zerov;
#pragma unroll
          for (int m = 0; m < 4; ++m)
            acc[m][q] = __builtin_amdgcn_mfma_f32_16x16x32_bf16(av[m], bv,
                                                                acc[m][q], 0, 0, 0);
        }
      }
    }
    __syncthreads();  // readers done + stage drained; buffers swap
  }

  // epilogue: C/D layout col=lane&15 (w), row=4*(lane>>4)+reg (oc offset)
  const int hrow = h0 + wv;
  float nzv[4];
#pragma unroll
  for (int q = 0; q < 4; ++q)
    nzv[q] = noise[b * 4096 + hrow * 64 + q * 16 + (lane & 15)];
#pragma unroll
  for (int m = 0; m < 4; ++m) {
#pragma unroll
    for (int reg = 0; reg < 4; ++reg) {
      const int oc = oc0 + m * 16 + (lane >> 4) * 4 + reg;
      const float dm = demod[b * 256 + oc];
      const float nwv = nw[oc];
      const float bvv = bias[oc];
#pragma unroll
      for (int q = 0; q < 4; ++q) {
        float v = acc[m][q][reg] * dm + nwv * nzv[q] + bvv;
        v = (v >= 0.f) ? v : 0.2f * v;
        out[((b * 256 + oc) * 64 + hrow) * 64 + q * 16 + (lane & 15)] = v;
      }
    }
  }
}

extern "C" void kernel_launch(void* const* d_in, const int* in_sizes, int n_in,
                              void* d_out, int out_size, void* d_ws, size_t ws_size,
                              hipStream_t stream) {
  const float* x     = (const float*)d_in[0];  // [8,256,64,64]
  const float* w     = (const float*)d_in[1];  // [8,512]
  const float* noise = (const float*)d_in[2];  // [8,1,64,64]
  const float* sw    = (const float*)d_in[3];  // [256,512]
  const float* sb    = (const float*)d_in[4];  // [256]
  const float* cw    = (const float*)d_in[5];  // [256,256,3,3]
  const float* nw    = (const float*)d_in[6];  // [256]
  const float* bias  = (const float*)d_in[7];  // [256]
  float* out = (float*)d_out;                  // [8,256,64,64]

  char* ws = (char*)d_ws;
  float* s            = (float*)(ws);            // 8 KB
  float* demod        = (float*)(ws + 8192);     // 8 KB
  unsigned* zbuf      = (unsigned*)(ws + 16384); // 1 KB zeros
  __hip_bfloat16* wt2 = (__hip_bfloat16*)(ws + 17408);    // 1.18 MB
  __hip_bfloat16* xt  = (__hip_bfloat16*)(ws + 1197056);  // 16.8 MB

  // Unconditional (no static guards — harness requires identical work/call).
  hipFuncSetAttribute((const void*)conv_mfma_kernel,
                      hipFuncAttributeMaxDynamicSharedMemorySize, 155648);

  style2_kernel<<<256, 256, 0, stream>>>(w, sw, sb, s, zbuf);
  wdm_kernel<<<256, 256, 0, stream>>>(cw, s, wt2, demod);
  xmod_kernel<<<dim3(64, 8), 256, 0, stream>>>(x, s, xt);
  conv_mfma_kernel<<<dim3(8, 4, 8), 512, 155648, stream>>>(
      xt, wt2, demod, noise, nw, bias, (const __hip_bfloat16*)zbuf, out);
}